// Round 5
// baseline (227.796 us; speedup 1.0000x reference)
//
#include <hip/hip_runtime.h>
#include <hip/hip_bf16.h>
#include <stdint.h>

typedef __attribute__((ext_vector_type(8))) short short8;
typedef __attribute__((ext_vector_type(4))) float float4v;
typedef __attribute__((ext_vector_type(4))) unsigned short ushort4v;

#define Bq 2
#define Sq 2048
#define Dq 1024
#define Hq 16
#define HDq 64

// 0.125 * log2(e): folded into Q at the QKV-GEMM epilogue so attention can use
// exp2 directly with no per-score scaling.
#define QSCALE 0.18033688011112042f

__device__ __forceinline__ unsigned short f2bf(float f) {
  union { float f; uint32_t u; } v; v.f = f;
  uint32_t r = (v.u + 0x7FFFu + ((v.u >> 16) & 1u)) >> 16;
  return (unsigned short)r;
}

// packed f32x2 -> bf16x2 (v_cvt_pk_bf16_f32 on gfx950)
__device__ __forceinline__ uint32_t pk2bf(float a, float b) {
  union { __hip_bfloat162 h; uint32_t u; } cv;
  cv.h = __float22bfloat162_rn(make_float2(a, b));
  return cv.u;
}

// async global->LDS, 16B per lane; LDS dest is wave-uniform base + lane*16.
__device__ __forceinline__ void gl_lds16(const unsigned short* g, unsigned short* l) {
  __builtin_amdgcn_global_load_lds(
      (const __attribute__((address_space(1))) void*)g,
      (__attribute__((address_space(3))) void*)l, 16, 0, 0);
}

// One launch: x (blocks 0..4095) + 4 weights (blocks 4096..8191, contiguous dst).
__global__ __launch_bounds__(256) void cvt_all_kernel(
    const float* __restrict__ x,
    const float* __restrict__ w0, const float* __restrict__ w1,
    const float* __restrict__ w2, const float* __restrict__ w3,
    unsigned short* __restrict__ xb, unsigned short* __restrict__ wb) {
  const int bid = blockIdx.x;
  const float* src;
  unsigned short* dst;
  int idx;
  if (bid < 4096) {
    src = x; dst = xb;
    idx = bid * 256 + threadIdx.x;
  } else {
    int j = (bid - 4096) * 256 + threadIdx.x;  // float4 index across 4 weights
    int z = j >> 18;                           // 262144 float4 per weight
    src = (z == 0) ? w0 : (z == 1) ? w1 : (z == 2) ? w2 : w3;
    dst = wb + (size_t)z * 1048576;            // 1M shorts per weight
    idx = j & 262143;
  }
  float4v f = ((const float4v*)src)[idx];
  ushort4v o;
#pragma unroll
  for (int q = 0; q < 4; q++) o[q] = f2bf(f[q]);
  ((ushort4v*)dst)[idx] = o;
}

// C = A(bf16 MxK) @ W^T. MT x 128 tile, BK=64, global_load_lds staging.
// LDS layout XOR-swizzled on 16B granules (phys_g = g ^ (row&7)): at 128B row
// stride unswizzled b128 frag reads are 16-way bank conflicts; swizzled 2-way
// (free). Staging side absorbs the swizzle in the precomputed global address.
// QKV epilogue scales Q (z==0) by QSCALE in fp32 before bf16 rounding.
template <bool OUTPROJ, int MT>
__global__ __launch_bounds__(256) void gemm_bt_kernel(
    const unsigned short* __restrict__ A,
    const unsigned short* __restrict__ W0,
    const unsigned short* __restrict__ W1,
    const unsigned short* __restrict__ W2,
    unsigned short* __restrict__ q_dst,
    unsigned short* __restrict__ k_dst,
    unsigned short* __restrict__ v_dst,
    float* __restrict__ f_dst,
    const float* __restrict__ bias) {
  constexpr int K = 1024;
  constexpr int NMB = MT / 32;    // 16-row m-blocks per wave
  constexpr int APASS = MT / 32;  // staging passes for A (32 rows each)
  const int z = blockIdx.z;
  const unsigned short* W = (z == 0) ? W0 : (z == 1) ? W1 : W2;
  unsigned short* qkv = (z == 0) ? q_dst : (z == 1) ? k_dst : v_dst;

  __shared__ unsigned short Asm[MT * 64];
  __shared__ unsigned short Bsm[128 * 64];

  const int t = threadIdx.x;
  const int wave = t >> 6, lane = t & 63;
  const int quad = lane >> 4, l16 = lane & 15;
  const int wy = wave >> 1, wx = wave & 1;
  const int row0 = blockIdx.x * MT;
  const int col0 = blockIdx.y * 128;

  float4v zero = {0.f, 0.f, 0.f, 0.f};
  float4v acc[NMB][4];
#pragma unroll
  for (int i = 0; i < NMB; i++)
#pragma unroll
    for (int j = 0; j < 4; j++) acc[i][j] = zero;

  // staging geometry: pass i covers rows i*32..i*32+31; thread t -> row i*32+(t>>3),
  // phys granule t&7, logical granule (t&7)^((t>>3)&7). LDS slot = i*2048 + t*8.
  const int srow = t >> 3;
  const int sgl = ((t & 7) ^ (srow & 7)) << 3;  // logical col in shorts
  const unsigned short* gA[APASS];
  const unsigned short* gB[4];
#pragma unroll
  for (int i = 0; i < APASS; i++)
    gA[i] = A + (size_t)(row0 + i * 32 + srow) * K + sgl;
#pragma unroll
  for (int i = 0; i < 4; i++)
    gB[i] = W + (size_t)(col0 + i * 32 + srow) * K + sgl;

  const int swl = (l16 & 7);  // frag-read swizzle key

  for (int k0 = 0; k0 < K; k0 += 64) {
#pragma unroll
    for (int i = 0; i < APASS; i++) gl_lds16(gA[i] + k0, &Asm[i * 2048 + t * 8]);
#pragma unroll
    for (int i = 0; i < 4; i++) gl_lds16(gB[i] + k0, &Bsm[i * 2048 + t * 8]);
    __syncthreads();
    short8 af[NMB][2], bf[4][2];
#pragma unroll
    for (int ks = 0; ks < 2; ks++) {
#pragma unroll
      for (int mb = 0; mb < NMB; mb++) {
        int row = wy * (MT / 2) + mb * 16 + l16;
        int pg = (ks * 4 + quad) ^ swl;
        af[mb][ks] = *(const short8*)(&Asm[row * 64 + pg * 8]);
      }
#pragma unroll
      for (int nb = 0; nb < 4; nb++) {
        int row = wx * 64 + nb * 16 + l16;
        int pg = (ks * 4 + quad) ^ swl;
        bf[nb][ks] = *(const short8*)(&Bsm[row * 64 + pg * 8]);
      }
    }
#pragma unroll
    for (int ks = 0; ks < 2; ks++)
#pragma unroll
      for (int mb = 0; mb < NMB; mb++)
#pragma unroll
        for (int nb = 0; nb < 4; nb++)
          acc[mb][nb] = __builtin_amdgcn_mfma_f32_16x16x32_bf16(af[mb][ks], bf[nb][ks], acc[mb][nb], 0, 0, 0);
    __syncthreads();
  }

  const float qsc = (!OUTPROJ && z == 0) ? QSCALE : 1.0f;
#pragma unroll
  for (int mb = 0; mb < NMB; mb++) {
#pragma unroll
    for (int nb = 0; nb < 4; nb++) {
#pragma unroll
      for (int r = 0; r < 4; r++) {
        int row = row0 + wy * (MT / 2) + mb * 16 + quad * 4 + r;  // token index
        int o = col0 + wx * 64 + nb * 16 + l16;                   // output feature
        float val = acc[mb][nb][r];
        if (OUTPROJ) {
          f_dst[(size_t)row * 1024 + o] = val + bias[o];
        } else {
          int b = row >> 11, s = row & 2047;
          int h = o >> 6, hd = o & 63;
          qkv[(size_t)((b * Hq + h) * Sq + s) * HDq + hd] = f2bf(val * qsc);
        }
      }
    }
  }
}

// Flash attention v6: K entirely off the LDS pipe.
// 512 threads, 8 waves = 4 q-groups x 2 key-groups (as v5), but K fragments
// are loaded DIRECTLY from global into registers (double-buffered one tile
// ahead): the A-operand frag K[key=s*16+l16][ks*32+quad*8] is loadable as a
// plain b128 — bit-identical values to v5's swizzled-LDS round trip (the XOR
// swizzle cancels on read). K/bh = 256 KB and is served by the XCD L2 (135
// B/cyc/CU > LDS 85 B/cyc) on a pipe that doesn't contend with V reads.
// LDS holds only V (v5's verified sigma-permuted v_perm pack, VSTR=136),
// double-buffered, one barrier per tile. LDS/block 67.5 -> 34.8 KB.
// Grid flattened to 512 with bijective XCD swizzle: bh = (wgid&7)*4 +
// (wgid>>3)/16 co-locates all 16 q-blocks of a bh on one XCD -> its Q/K/V
// (~3 MB) lives in that XCD's 4 MB L2.
// Epilogue: v5's verified wk-partial combine (obuf/dbuf overlay Vsm).
__global__ __launch_bounds__(512, 4) void attn_kernel(
    const unsigned short* __restrict__ Q,
    const unsigned short* __restrict__ Kg,
    const unsigned short* __restrict__ Vg,
    unsigned short* __restrict__ ctx) {
  constexpr int VSTR = 136;   // Vsm stride (shorts)
  constexpr int VBUF = 8704;  // shorts per V buffer (64 x 136)
  constexpr int QSTR = 132;   // obuf q-dim stride (f32)
  __shared__ __align__(16) unsigned char smem[34816];
  unsigned short* Vsm = (unsigned short*)smem;   // [2][8704] shorts
  float* obuf = (float*)smem;                    // combine: [64 hd][132 q]
  float* dbuf = (float*)(smem + 33792);          // combine: [128]

  const int wgid = blockIdx.x;
  const int lid = wgid >> 3;
  const int bh = (wgid & 7) * 4 + (lid >> 4);  // XCD-co-located bh
  const int q0 = (lid & 15) * 128;
  const int t = threadIdx.x;
  const int wave = t >> 6, lane = t & 63;
  const int quad = lane >> 4, l16 = lane & 15;
  const int wq = wave >> 1, wk = wave & 1;

  const unsigned short* Qb = Q + (size_t)bh * Sq * HDq;
  const unsigned short* Kb = Kg + (size_t)bh * Sq * HDq;
  const unsigned short* Vb = Vg + (size_t)bh * Sq * HDq;

  // Q fragments: wave's 32 q rows (B-operand of QK^T S^T-trick MFMA)
  short8 qf[2][2];
#pragma unroll
  for (int qb = 0; qb < 2; qb++)
#pragma unroll
    for (int ks = 0; ks < 2; ks++)
      qf[qb][ks] = *(const short8*)(Qb + (size_t)(q0 + wq * 32 + qb * 16 + l16) * HDq + ks * 32 + quad * 8);

  short8 ones;
#pragma unroll
  for (int j = 0; j < 8; j++) ones[j] = (short)0x3F80;  // bf16 1.0

  float4v zero = {0.f, 0.f, 0.f, 0.f};
  float4v of[2][4];   // [qb][hb]; D layout row=q (quad*4+r), col=hd (l16)
  float4v dsum[2];
#pragma unroll
  for (int qb = 0; qb < 2; qb++) {
    dsum[qb] = zero;
#pragma unroll
    for (int hb = 0; hb < 4; hb++) of[qb][hb] = zero;
  }

  // K fragment base: kf[p][s][ks] = Kb[(kt + wk*64 + p*32 + s*16 + l16)*64
  //                                    + ks*32 + quad*8]
  const unsigned short* gKf = Kb + (size_t)(wk * 64 + l16) * HDq + quad * 8;

  // V staging (v5-verified): thread t covers keys vr2, vr2+1 at hd slice
  // vc8..vc8+7 (wave-indexed); sigma permutes key -> column for PV b128 frags.
  const int vr2 = (t & 63) * 2;
  const int vc8 = (t >> 6) << 3;
  const int sig = (vr2 & ~31) + (((vr2 >> 2) & 3) << 3) + (((vr2 >> 4) & 1) << 2) + (vr2 & 3);
  const unsigned short* gV = Vb + (size_t)vr2 * HDq + vc8;

  short8 vpr0, vpr1;
  short8 ka[8], kb_[8];  // K tile double buffer, idx = p*4 + s*2 + ks

#define VLOAD(off) do {                                              \
    const unsigned short* vp = gV + (size_t)(off) * HDq;             \
    vpr0 = *(const short8*)(vp);                                     \
    vpr1 = *(const short8*)(vp + HDq);                               \
  } while (0)

#define VPACK(bufsel) do {                                           \
    unsigned short* vd = &Vsm[(bufsel) * VBUF + sig];                \
    _Pragma("unroll")                                                \
    for (int j = 0; j < 8; j++) {                                    \
      uint32_t pk = (uint32_t)(unsigned short)vpr0[j] |              \
                    ((uint32_t)(unsigned short)vpr1[j] << 16);       \
      *(uint32_t*)(vd + (vc8 + j) * VSTR) = pk;                      \
    }                                                                \
  } while (0)

#define KLOAD(dst, KT) do {                                          \
    const unsigned short* kp_ = gKf + (size_t)(KT) * HDq;            \
    _Pragma("unroll")                                                \
    for (int p_ = 0; p_ < 2; p_++)                                   \
      _Pragma("unroll")                                              \
      for (int s_ = 0; s_ < 2; s_++)                                 \
        _Pragma("unroll")                                            \
        for (int ks_ = 0; ks_ < 2; ks_++)                            \
          dst[p_ * 4 + s_ * 2 + ks_] =                               \
              *(const short8*)(kp_ + p_ * 2048 + s_ * 1024 + ks_ * 32); \
  } while (0)

  // one 32-key substep from register K + LDS V
#define PSTEP(kreg, P, BUF) do {                                               \
    short8 pf[2];                                                              \
    _Pragma("unroll")                                                          \
    for (int qb = 0; qb < 2; qb++) {                                           \
      float4v sa = zero, sb = zero;                                            \
      _Pragma("unroll")                                                        \
      for (int ks = 0; ks < 2; ks++) {                                         \
        sa = __builtin_amdgcn_mfma_f32_16x16x32_bf16(kreg[(P) * 4 + ks], qf[qb][ks], sa, 0, 0, 0);     \
        sb = __builtin_amdgcn_mfma_f32_16x16x32_bf16(kreg[(P) * 4 + 2 + ks], qf[qb][ks], sb, 0, 0, 0); \
      }                                                                        \
      union { uint32_t u[4]; short8 v; } pw;                                   \
      pw.u[0] = pk2bf(__builtin_amdgcn_exp2f(sa[0]), __builtin_amdgcn_exp2f(sa[1])); \
      pw.u[1] = pk2bf(__builtin_amdgcn_exp2f(sa[2]), __builtin_amdgcn_exp2f(sa[3])); \
      pw.u[2] = pk2bf(__builtin_amdgcn_exp2f(sb[0]), __builtin_amdgcn_exp2f(sb[1])); \
      pw.u[3] = pk2bf(__builtin_amdgcn_exp2f(sb[2]), __builtin_amdgcn_exp2f(sb[3])); \
      pf[qb] = pw.v;                                                           \
    }                                                                          \
    _Pragma("unroll")                                                          \
    for (int qb = 0; qb < 2; qb++)                                             \
      dsum[qb] = __builtin_amdgcn_mfma_f32_16x16x32_bf16(pf[qb], ones, dsum[qb], 0, 0, 0); \
    const int vbo = (BUF) * VBUF + wk * 64 + (P) * 32 + quad * 8;              \
    _Pragma("unroll")                                                          \
    for (int hb = 0; hb < 4; hb++) {                                           \
      short8 vf = *(const short8*)&Vsm[vbo + (hb * 16 + l16) * VSTR];          \
      _Pragma("unroll")                                                        \
      for (int qb = 0; qb < 2; qb++)                                           \
        of[qb][hb] = __builtin_amdgcn_mfma_f32_16x16x32_bf16(pf[qb], vf, of[qb][hb], 0, 0, 0); \
    }                                                                          \
  } while (0)

  // full 128-key tile: prefetch next K tile into the spare register buffer,
  // compute 2 substeps from current, stage next V, one barrier.
  // Last tile's KLOAD reads 8KB past this bh's K (lands in the V workspace
  // region - mapped, values unused).
#define TILE(kc, kn, KT, BUF) do {                                   \
    KLOAD(kn, (KT) + 128);                                           \
    PSTEP(kc, 0, BUF);                                               \
    PSTEP(kc, 1, BUF);                                               \
    if ((KT) + 128 < Sq) VPACK((BUF) ^ 1);                           \
    if ((KT) + 256 < Sq) VLOAD((KT) + 256);                          \
    __syncthreads();                                                 \
  } while (0)

  // prologue: K tile 0 + V tile 0 staged; V tile 1 in regs.
  KLOAD(ka, 0);
  VLOAD(0);
  VPACK(0);
  VLOAD(128);
  __syncthreads();

  for (int kt = 0; kt < Sq; kt += 256) {
    TILE(ka, kb_, kt, 0);
    TILE(kb_, ka, kt + 128, 1);
  }

  // combine the 2 key-group partials in LDS: obuf[hd][q] f32, float4 stores
  // along q (quad*4+r contiguous). Overlays Vsm (safe after final barrier).
  if (wk == 0) {
#pragma unroll
    for (int qb = 0; qb < 2; qb++) {
#pragma unroll
      for (int hb = 0; hb < 4; hb++)
        *(float4v*)&obuf[(hb * 16 + l16) * QSTR + wq * 32 + qb * 16 + quad * 4] = of[qb][hb];
      if (l16 == 0)
#pragma unroll
        for (int r = 0; r < 4; r++)
          dbuf[wq * 32 + qb * 16 + quad * 4 + r] = dsum[qb][r];
    }
  }
  __syncthreads();
  if (wk == 1) {
#pragma unroll
    for (int qb = 0; qb < 2; qb++) {
#pragma unroll
      for (int hb = 0; hb < 4; hb++) {
        float4v* pp = (float4v*)&obuf[(hb * 16 + l16) * QSTR + wq * 32 + qb * 16 + quad * 4];
        float4v o = *pp;
        o += of[qb][hb];
        *pp = o;
      }
      if (l16 == 0)
#pragma unroll
        for (int r = 0; r < 4; r++)
          dbuf[wq * 32 + qb * 16 + quad * 4 + r] += dsum[qb][r];
    }
  }
  __syncthreads();

  // final store: thread t -> q row (t&127), 16-hd segment (t>>7)
  const int b = bh >> 4, h = bh & 15;
  const int qq = t & 127, hseg = t >> 7;
  const float dinv = 1.0f / dbuf[qq];
  unsigned short* cp = ctx + ((size_t)(b * Sq + q0 + qq)) * Dq + h * 64 + hseg * 16;
  short8 o8a, o8b;
#pragma unroll
  for (int j = 0; j < 8; j++) o8a[j] = (short)f2bf(obuf[(hseg * 16 + j) * QSTR + qq] * dinv);
#pragma unroll
  for (int j = 0; j < 8; j++) o8b[j] = (short)f2bf(obuf[(hseg * 16 + 8 + j) * QSTR + qq] * dinv);
  *(short8*)cp = o8a;
  *(short8*)(cp + 8) = o8b;
#undef VLOAD
#undef VPACK
#undef KLOAD
#undef PSTEP
#undef TILE
}

extern "C" void kernel_launch(void* const* d_in, const int* in_sizes, int n_in,
                              void* d_out, int out_size, void* d_ws, size_t ws_size,
                              hipStream_t stream) {
  (void)in_sizes; (void)n_in; (void)out_size; (void)ws_size;
  const float* x  = (const float*)d_in[0];
  const float* wq = (const float*)d_in[1];
  const float* wk = (const float*)d_in[2];
  const float* wv = (const float*)d_in[3];
  const float* wo = (const float*)d_in[4];
  const float* bo = (const float*)d_in[5];
  float* out = (float*)d_out;

  char* ws = (char*)d_ws;
  const size_t MB = 1u << 20;
  unsigned short* xb  = (unsigned short*)(ws + 0 * MB);   // 8 MB  (4096x1024 bf16)
  unsigned short* wqb = (unsigned short*)(ws + 8 * MB);   // 2 MB each, contiguous
  unsigned short* wkb = (unsigned short*)(ws + 10 * MB);
  unsigned short* wvb = (unsigned short*)(ws + 12 * MB);
  unsigned short* wob = (unsigned short*)(ws + 14 * MB);
  unsigned short* qb  = (unsigned short*)(ws + 16 * MB);  // 8 MB  (B,H,S,HD), pre-scaled
  unsigned short* kb  = (unsigned short*)(ws + 24 * MB);  // 8 MB
  unsigned short* vb  = (unsigned short*)(ws + 32 * MB);  // 8 MB
  unsigned short* cxb = (unsigned short*)(ws + 40 * MB);  // 8 MB  (B,S,D)

  cvt_all_kernel<<<8192, 256, 0, stream>>>(x, wq, wk, wv, wo, xb, wqb);

  gemm_bt_kernel<false, 128><<<dim3(32, 8, 3), 256, 0, stream>>>(
      xb, wqb, wkb, wvb, qb, kb, vb, nullptr, nullptr);
  attn_kernel<<<dim3(512), 512, 0, stream>>>(qb, kb, vb, cxb);
  gemm_bt_kernel<true, 64><<<dim3(64, 8, 1), 256, 0, stream>>>(
      cxb, wob, wob, wob, nullptr, nullptr, nullptr, out, bo);
}

// Round 6
// 187.590 us; speedup vs baseline: 1.2143x; 1.2143x over previous
//
#include <hip/hip_runtime.h>
#include <hip/hip_bf16.h>
#include <stdint.h>

typedef __attribute__((ext_vector_type(8))) short short8;
typedef __attribute__((ext_vector_type(4))) float float4v;
typedef __attribute__((ext_vector_type(4))) unsigned short ushort4v;

#define Bq 2
#define Sq 2048
#define Dq 1024
#define Hq 16
#define HDq 64

// 0.125 * log2(e): folded into Q at the QKV-GEMM epilogue so attention can use
// exp2 directly with no per-score scaling.
#define QSCALE 0.18033688011112042f

__device__ __forceinline__ unsigned short f2bf(float f) {
  union { float f; uint32_t u; } v; v.f = f;
  uint32_t r = (v.u + 0x7FFFu + ((v.u >> 16) & 1u)) >> 16;
  return (unsigned short)r;
}

// packed f32x2 -> bf16x2 (v_cvt_pk_bf16_f32 on gfx950)
__device__ __forceinline__ uint32_t pk2bf(float a, float b) {
  union { __hip_bfloat162 h; uint32_t u; } cv;
  cv.h = __float22bfloat162_rn(make_float2(a, b));
  return cv.u;
}

// async global->LDS, 16B per lane; LDS dest is wave-uniform base + lane*16.
__device__ __forceinline__ void gl_lds16(const unsigned short* g, unsigned short* l) {
  __builtin_amdgcn_global_load_lds(
      (const __attribute__((address_space(1))) void*)g,
      (__attribute__((address_space(3))) void*)l, 16, 0, 0);
}

// One launch: x (blocks 0..4095) + 4 weights (blocks 4096..8191, contiguous dst).
__global__ __launch_bounds__(256) void cvt_all_kernel(
    const float* __restrict__ x,
    const float* __restrict__ w0, const float* __restrict__ w1,
    const float* __restrict__ w2, const float* __restrict__ w3,
    unsigned short* __restrict__ xb, unsigned short* __restrict__ wb) {
  const int bid = blockIdx.x;
  const float* src;
  unsigned short* dst;
  int idx;
  if (bid < 4096) {
    src = x; dst = xb;
    idx = bid * 256 + threadIdx.x;
  } else {
    int j = (bid - 4096) * 256 + threadIdx.x;  // float4 index across 4 weights
    int z = j >> 18;                           // 262144 float4 per weight
    src = (z == 0) ? w0 : (z == 1) ? w1 : (z == 2) ? w2 : w3;
    dst = wb + (size_t)z * 1048576;            // 1M shorts per weight
    idx = j & 262143;
  }
  float4v f = ((const float4v*)src)[idx];
  ushort4v o;
#pragma unroll
  for (int q = 0; q < 4; q++) o[q] = f2bf(f[q]);
  ((ushort4v*)dst)[idx] = o;
}

// C = A(bf16 MxK) @ W^T. MT x 128 tile, BK=64, global_load_lds staging.
// LDS layout XOR-swizzled on 16B granules (phys_g = g ^ (row&7)): at 128B row
// stride unswizzled b128 frag reads are 16-way bank conflicts; swizzled 2-way
// (free). Staging side absorbs the swizzle in the precomputed global address.
// QKV epilogue scales Q (z==0) by QSCALE in fp32 before bf16 rounding.
template <bool OUTPROJ, int MT>
__global__ __launch_bounds__(256) void gemm_bt_kernel(
    const unsigned short* __restrict__ A,
    const unsigned short* __restrict__ W0,
    const unsigned short* __restrict__ W1,
    const unsigned short* __restrict__ W2,
    unsigned short* __restrict__ q_dst,
    unsigned short* __restrict__ k_dst,
    unsigned short* __restrict__ v_dst,
    float* __restrict__ f_dst,
    const float* __restrict__ bias) {
  constexpr int K = 1024;
  constexpr int NMB = MT / 32;    // 16-row m-blocks per wave
  constexpr int APASS = MT / 32;  // staging passes for A (32 rows each)
  const int z = blockIdx.z;
  const unsigned short* W = (z == 0) ? W0 : (z == 1) ? W1 : W2;
  unsigned short* qkv = (z == 0) ? q_dst : (z == 1) ? k_dst : v_dst;

  __shared__ unsigned short Asm[MT * 64];
  __shared__ unsigned short Bsm[128 * 64];

  const int t = threadIdx.x;
  const int wave = t >> 6, lane = t & 63;
  const int quad = lane >> 4, l16 = lane & 15;
  const int wy = wave >> 1, wx = wave & 1;
  const int row0 = blockIdx.x * MT;
  const int col0 = blockIdx.y * 128;

  float4v zero = {0.f, 0.f, 0.f, 0.f};
  float4v acc[NMB][4];
#pragma unroll
  for (int i = 0; i < NMB; i++)
#pragma unroll
    for (int j = 0; j < 4; j++) acc[i][j] = zero;

  // staging geometry: pass i covers rows i*32..i*32+31; thread t -> row i*32+(t>>3),
  // phys granule t&7, logical granule (t&7)^((t>>3)&7). LDS slot = i*2048 + t*8.
  const int srow = t >> 3;
  const int sgl = ((t & 7) ^ (srow & 7)) << 3;  // logical col in shorts
  const unsigned short* gA[APASS];
  const unsigned short* gB[4];
#pragma unroll
  for (int i = 0; i < APASS; i++)
    gA[i] = A + (size_t)(row0 + i * 32 + srow) * K + sgl;
#pragma unroll
  for (int i = 0; i < 4; i++)
    gB[i] = W + (size_t)(col0 + i * 32 + srow) * K + sgl;

  const int swl = (l16 & 7);  // frag-read swizzle key

  for (int k0 = 0; k0 < K; k0 += 64) {
#pragma unroll
    for (int i = 0; i < APASS; i++) gl_lds16(gA[i] + k0, &Asm[i * 2048 + t * 8]);
#pragma unroll
    for (int i = 0; i < 4; i++) gl_lds16(gB[i] + k0, &Bsm[i * 2048 + t * 8]);
    __syncthreads();
    short8 af[NMB][2], bf[4][2];
#pragma unroll
    for (int ks = 0; ks < 2; ks++) {
#pragma unroll
      for (int mb = 0; mb < NMB; mb++) {
        int row = wy * (MT / 2) + mb * 16 + l16;
        int pg = (ks * 4 + quad) ^ swl;
        af[mb][ks] = *(const short8*)(&Asm[row * 64 + pg * 8]);
      }
#pragma unroll
      for (int nb = 0; nb < 4; nb++) {
        int row = wx * 64 + nb * 16 + l16;
        int pg = (ks * 4 + quad) ^ swl;
        bf[nb][ks] = *(const short8*)(&Bsm[row * 64 + pg * 8]);
      }
    }
#pragma unroll
    for (int ks = 0; ks < 2; ks++)
#pragma unroll
      for (int mb = 0; mb < NMB; mb++)
#pragma unroll
        for (int nb = 0; nb < 4; nb++)
          acc[mb][nb] = __builtin_amdgcn_mfma_f32_16x16x32_bf16(af[mb][ks], bf[nb][ks], acc[mb][nb], 0, 0, 0);
    __syncthreads();
  }

  const float qsc = (!OUTPROJ && z == 0) ? QSCALE : 1.0f;
#pragma unroll
  for (int mb = 0; mb < NMB; mb++) {
#pragma unroll
    for (int nb = 0; nb < 4; nb++) {
#pragma unroll
      for (int r = 0; r < 4; r++) {
        int row = row0 + wy * (MT / 2) + mb * 16 + quad * 4 + r;  // token index
        int o = col0 + wx * 64 + nb * 16 + l16;                   // output feature
        float val = acc[mb][nb][r];
        if (OUTPROJ) {
          f_dst[(size_t)row * 1024 + o] = val + bias[o];
        } else {
          int b = row >> 11, s = row & 2047;
          int h = o >> 6, hd = o & 63;
          qkv[(size_t)((b * Hq + h) * Sq + s) * HDq + hd] = f2bf(val * qsc);
        }
      }
    }
  }
}

// Flash attention v7: v5 memory structure (both K and V staged in LDS, all
// verified paths) + anti-lockstep scheduling.
// 512 threads, 8 waves = 4 q-groups x 2 key-groups; each wave 32q x 64keys.
// v5 measured ~full pipe serialization (55us vs ~29us overlap floor): all
// waves march in lockstep through {ds_read | MFMA | exp2} phases so only one
// pipe is hot at a time. v7 adds:
//  (1) phase stagger: waves with (wave>>1)&1 process the two 32-key substeps
//      in reverse order (substeps are independent, accumulate into the same
//      of/dsum -> order-invariant); each SIMD then hosts waves in opposite
//      phases, overlapping LDS/MFMA/trans pipes.
//  (2) s_setprio(1) around MFMA clusters (T5; needs (1)'s role diversity).
//  (3) early VLOAD + vprA/vprB double buffer: V global loads issue at tile
//      start, latency hides under compute, barrier drain ~free.
//  (4) v6-validated XCD-swizzled flat grid: bh co-located per XCD so K/V
//      re-reads hit that XCD's L2 (FETCH 70->16MB measured in v6).
// Epilogue: v5's verified wk-partial combine (obuf/dbuf overlay).
__global__ __launch_bounds__(512, 4) void attn_kernel(
    const unsigned short* __restrict__ Q,
    const unsigned short* __restrict__ Kg,
    const unsigned short* __restrict__ Vg,
    unsigned short* __restrict__ ctx) {
  constexpr int VSTR = 136;   // Vsm stride (shorts)
  constexpr int KBUF = 8192;  // shorts per K buffer (128 keys x 64 hd, swizzled)
  constexpr int VBUF = 8704;  // shorts per V buffer (64 x 136)
  constexpr int QSTR = 132;   // obuf q-dim stride (f32)
  __shared__ __align__(16) unsigned char smem[67584];
  unsigned short* Ksm = (unsigned short*)smem;            // [2][8192]
  unsigned short* Vsm = (unsigned short*)(smem + 32768);  // [2][8704]
  float* obuf = (float*)smem;                             // combine: [64 hd][132 q]
  float* dbuf = (float*)(smem + 33792);                   // combine: [128]

  const int wgid = blockIdx.x;
  const int lid = wgid >> 3;
  const int bh = (wgid & 7) * 4 + (lid >> 4);  // XCD-co-located bh
  const int q0 = (lid & 15) * 128;
  const int t = threadIdx.x;
  const int wave = t >> 6, lane = t & 63;
  const int quad = lane >> 4, l16 = lane & 15;
  const int wq = wave >> 1, wk = wave & 1;
  const int swl = l16 & 7;
  const int pfirst = (wave >> 1) & 1;  // substep stagger key

  const unsigned short* Qb = Q + (size_t)bh * Sq * HDq;
  const unsigned short* Kb = Kg + (size_t)bh * Sq * HDq;
  const unsigned short* Vb = Vg + (size_t)bh * Sq * HDq;

  // Q fragments: wave's 32 q rows (B-operand of QK^T S^T-trick MFMA)
  short8 qf[2][2];
#pragma unroll
  for (int qb = 0; qb < 2; qb++)
#pragma unroll
    for (int ks = 0; ks < 2; ks++)
      qf[qb][ks] = *(const short8*)(Qb + (size_t)(q0 + wq * 32 + qb * 16 + l16) * HDq + ks * 32 + quad * 8);

  short8 ones;
#pragma unroll
  for (int j = 0; j < 8; j++) ones[j] = (short)0x3F80;  // bf16 1.0

  float4v zero = {0.f, 0.f, 0.f, 0.f};
  float4v of[2][4];   // [qb][hb]; D layout row=q (quad*4+r), col=hd (l16)
  float4v dsum[2];
#pragma unroll
  for (int qb = 0; qb < 2; qb++) {
    dsum[qb] = zero;
#pragma unroll
    for (int hb = 0; hb < 4; hb++) of[qb][hb] = zero;
  }

  // K staging: 2 passes x 512 threads x 16B. Pass i row = i*64 + (t>>3);
  // XOR swizzle on 16B granules pre-applied to the global address.
  const int srow = t >> 3;
  const unsigned short* gK = Kb + (size_t)srow * 64 + (((t & 7) ^ (srow & 7)) << 3);

  // V staging (v5-verified): thread t covers keys vr2, vr2+1 at hd slice
  // vc8..vc8+7 (wave-indexed); sigma permutes key -> column for PV b128 frags.
  const int vr2 = (t & 63) * 2;
  const int vc8 = (t >> 6) << 3;
  const int sig = (vr2 & ~31) + (((vr2 >> 2) & 3) << 3) + (((vr2 >> 4) & 1) << 2) + (vr2 & 3);
  const unsigned short* gV = Vb + (size_t)vr2 * HDq + vc8;

  short8 vprA0, vprA1, vprB0, vprB1;  // V prefetch double buffer

#define VLOADA(off) do {                                             \
    const unsigned short* vp = gV + (size_t)(off) * HDq;             \
    vprA0 = *(const short8*)(vp);                                    \
    vprA1 = *(const short8*)(vp + HDq);                              \
  } while (0)

#define VLOADB(off) do {                                             \
    const unsigned short* vp = gV + (size_t)(off) * HDq;             \
    vprB0 = *(const short8*)(vp);                                    \
    vprB1 = *(const short8*)(vp + HDq);                              \
  } while (0)

#define VPACK(bufsel, r0, r1) do {                                   \
    unsigned short* vd = &Vsm[(bufsel) * VBUF + sig];                \
    _Pragma("unroll")                                                \
    for (int j = 0; j < 8; j++) {                                    \
      uint32_t pk = (uint32_t)(unsigned short)r0[j] |                \
                    ((uint32_t)(unsigned short)r1[j] << 16);         \
      *(uint32_t*)(vd + (vc8 + j) * VSTR) = pk;                      \
    }                                                                \
  } while (0)

#define KISSUE(off, bufsel) do {                                     \
    gl_lds16(gK + (size_t)(off) * 64, &Ksm[(bufsel) * KBUF + t * 8]);\
    gl_lds16(gK + (size_t)(off) * 64 + 4096,                         \
             &Ksm[(bufsel) * KBUF + 4096 + t * 8]);                  \
  } while (0)

  // one 32-key substep (runtime P for stagger); accumulation is P-order
  // invariant. setprio(1) around the MFMA clusters.
#define PSTEP(P, BUF) do {                                                     \
    const int p_ = (P);                                                        \
    const int kb0 = (BUF) * KBUF + wk * 4096 + p_ * 2048;                      \
    short8 kf[2][2];                                                           \
    _Pragma("unroll")                                                          \
    for (int s = 0; s < 2; s++)                                                \
      _Pragma("unroll")                                                        \
      for (int ks = 0; ks < 2; ks++)                                           \
        kf[s][ks] = *(const short8*)&Ksm[kb0 + (s * 16 + l16) * 64 + ((ks * 4 + quad) ^ swl) * 8]; \
    short8 pfr[2];                                                             \
    _Pragma("unroll")                                                          \
    for (int qb = 0; qb < 2; qb++) {                                           \
      float4v sa = zero, sb = zero;                                            \
      __builtin_amdgcn_s_setprio(1);                                           \
      _Pragma("unroll")                                                        \
      for (int ks = 0; ks < 2; ks++) {                                         \
        sa = __builtin_amdgcn_mfma_f32_16x16x32_bf16(kf[0][ks], qf[qb][ks], sa, 0, 0, 0); \
        sb = __builtin_amdgcn_mfma_f32_16x16x32_bf16(kf[1][ks], qf[qb][ks], sb, 0, 0, 0); \
      }                                                                        \
      __builtin_amdgcn_s_setprio(0);                                           \
      union { uint32_t u[4]; short8 v; } pw;                                   \
      pw.u[0] = pk2bf(__builtin_amdgcn_exp2f(sa[0]), __builtin_amdgcn_exp2f(sa[1])); \
      pw.u[1] = pk2bf(__builtin_amdgcn_exp2f(sa[2]), __builtin_amdgcn_exp2f(sa[3])); \
      pw.u[2] = pk2bf(__builtin_amdgcn_exp2f(sb[0]), __builtin_amdgcn_exp2f(sb[1])); \
      pw.u[3] = pk2bf(__builtin_amdgcn_exp2f(sb[2]), __builtin_amdgcn_exp2f(sb[3])); \
      pfr[qb] = pw.v;                                                          \
    }                                                                          \
    __builtin_amdgcn_s_setprio(1);                                             \
    _Pragma("unroll")                                                          \
    for (int qb = 0; qb < 2; qb++)                                             \
      dsum[qb] = __builtin_amdgcn_mfma_f32_16x16x32_bf16(pfr[qb], ones, dsum[qb], 0, 0, 0); \
    const int vbo = (BUF) * VBUF + wk * 64 + p_ * 32 + quad * 8;               \
    _Pragma("unroll")                                                          \
    for (int hb = 0; hb < 4; hb++) {                                           \
      short8 vf = *(const short8*)&Vsm[vbo + (hb * 16 + l16) * VSTR];          \
      _Pragma("unroll")                                                        \
      for (int qb = 0; qb < 2; qb++)                                           \
        of[qb][hb] = __builtin_amdgcn_mfma_f32_16x16x32_bf16(pfr[qb], vf, of[qb][hb], 0, 0, 0); \
    }                                                                          \
    __builtin_amdgcn_s_setprio(0);                                             \
  } while (0)

  // prologue: K0 async + V0 pack into buf0; V1 -> vprB; barrier; K1 async.
  KISSUE(0, 0);
  VLOADA(0);
  VPACK(0, vprA0, vprA1);
  VLOADB(128);
  __syncthreads();
  KISSUE(128, 1);

  // 2-tile unrolled main loop; V regs alternate A/B, LDS buffers alternate 0/1.
  for (int kt = 0; kt < Sq; kt += 256) {
    // tile kt (buf 0): pack V(kt+128) from vprB, prefetch V(kt+256) -> vprA
    if (kt + 256 < Sq) VLOADA(kt + 256);
    PSTEP(pfirst, 0);
    PSTEP(pfirst ^ 1, 0);
    if (kt + 128 < Sq) VPACK(1, vprB0, vprB1);
    __syncthreads();
    if (kt + 256 < Sq) KISSUE(kt + 256, 0);
    // tile kt+128 (buf 1): pack V(kt+256) from vprA, prefetch V(kt+384) -> vprB
    if (kt + 384 < Sq) VLOADB(kt + 384);
    PSTEP(pfirst, 1);
    PSTEP(pfirst ^ 1, 1);
    if (kt + 256 < Sq) VPACK(0, vprA0, vprA1);
    __syncthreads();
    if (kt + 384 < Sq) KISSUE(kt + 384, 1);
  }

  // combine the 2 key-group partials in LDS: obuf[hd][q] f32, float4 stores
  // along q (quad*4+r contiguous). Overlays K/V buffers (safe after barrier).
  if (wk == 0) {
#pragma unroll
    for (int qb = 0; qb < 2; qb++) {
#pragma unroll
      for (int hb = 0; hb < 4; hb++)
        *(float4v*)&obuf[(hb * 16 + l16) * QSTR + wq * 32 + qb * 16 + quad * 4] = of[qb][hb];
      if (l16 == 0)
#pragma unroll
        for (int r = 0; r < 4; r++)
          dbuf[wq * 32 + qb * 16 + quad * 4 + r] = dsum[qb][r];
    }
  }
  __syncthreads();
  if (wk == 1) {
#pragma unroll
    for (int qb = 0; qb < 2; qb++) {
#pragma unroll
      for (int hb = 0; hb < 4; hb++) {
        float4v* pp = (float4v*)&obuf[(hb * 16 + l16) * QSTR + wq * 32 + qb * 16 + quad * 4];
        float4v o = *pp;
        o += of[qb][hb];
        *pp = o;
      }
      if (l16 == 0)
#pragma unroll
        for (int r = 0; r < 4; r++)
          dbuf[wq * 32 + qb * 16 + quad * 4 + r] += dsum[qb][r];
    }
  }
  __syncthreads();

  // final store: thread t -> q row (t&127), 16-hd segment (t>>7)
  const int b = bh >> 4, h = bh & 15;
  const int qq = t & 127, hseg = t >> 7;
  const float dinv = 1.0f / dbuf[qq];
  unsigned short* cp = ctx + ((size_t)(b * Sq + q0 + qq)) * Dq + h * 64 + hseg * 16;
  short8 o8a, o8b;
#pragma unroll
  for (int j = 0; j < 8; j++) o8a[j] = (short)f2bf(obuf[(hseg * 16 + j) * QSTR + qq] * dinv);
#pragma unroll
  for (int j = 0; j < 8; j++) o8b[j] = (short)f2bf(obuf[(hseg * 16 + 8 + j) * QSTR + qq] * dinv);
  *(short8*)cp = o8a;
  *(short8*)(cp + 8) = o8b;
#undef VLOADA
#undef VLOADB
#undef VPACK
#undef KISSUE
#undef PSTEP
}

extern "C" void kernel_launch(void* const* d_in, const int* in_sizes, int n_in,
                              void* d_out, int out_size, void* d_ws, size_t ws_size,
                              hipStream_t stream) {
  (void)in_sizes; (void)n_in; (void)out_size; (void)ws_size;
  const float* x  = (const float*)d_in[0];
  const float* wq = (const float*)d_in[1];
  const float* wk = (const float*)d_in[2];
  const float* wv = (const float*)d_in[3];
  const float* wo = (const float*)d_in[4];
  const float* bo = (const float*)d_in[5];
  float* out = (float*)d_out;

  char* ws = (char*)d_ws;
  const size_t MB = 1u << 20;
  unsigned short* xb  = (unsigned short*)(ws + 0 * MB);   // 8 MB  (4096x1024 bf16)
  unsigned short* wqb = (unsigned short*)(ws + 8 * MB);   // 2 MB each, contiguous
  unsigned short* wkb = (unsigned short*)(ws + 10 * MB);
  unsigned short* wvb = (unsigned short*)(ws + 12 * MB);
  unsigned short* wob = (unsigned short*)(ws + 14 * MB);
  unsigned short* qb  = (unsigned short*)(ws + 16 * MB);  // 8 MB  (B,H,S,HD), pre-scaled
  unsigned short* kb  = (unsigned short*)(ws + 24 * MB);  // 8 MB
  unsigned short* vb  = (unsigned short*)(ws + 32 * MB);  // 8 MB
  unsigned short* cxb = (unsigned short*)(ws + 40 * MB);  // 8 MB  (B,S,D)

  cvt_all_kernel<<<8192, 256, 0, stream>>>(x, wq, wk, wv, wo, xb, wqb);

  gemm_bt_kernel<false, 128><<<dim3(32, 8, 3), 256, 0, stream>>>(
      xb, wqb, wkb, wvb, qb, kb, vb, nullptr, nullptr);
  attn_kernel<<<dim3(512), 512, 0, stream>>>(qb, kb, vb, cxb);
  gemm_bt_kernel<true, 64><<<dim3(64, 8, 1), 256, 0, stream>>>(
      cxb, wob, wob, wob, nullptr, nullptr, nullptr, out, bo);
}

// Round 7
// 186.781 us; speedup vs baseline: 1.2196x; 1.0043x over previous
//
#include <hip/hip_runtime.h>
#include <hip/hip_bf16.h>
#include <stdint.h>

typedef __attribute__((ext_vector_type(8))) short short8;
typedef __attribute__((ext_vector_type(4))) float float4v;
typedef __attribute__((ext_vector_type(4))) unsigned short ushort4v;

#define Bq 2
#define Sq 2048
#define Dq 1024
#define Hq 16
#define HDq 64

// 0.125 * log2(e): folded into Q at the QKV-GEMM epilogue so attention can use
// exp2 directly with no per-score scaling.
#define QSCALE 0.18033688011112042f

__device__ __forceinline__ unsigned short f2bf(float f) {
  union { float f; uint32_t u; } v; v.f = f;
  uint32_t r = (v.u + 0x7FFFu + ((v.u >> 16) & 1u)) >> 16;
  return (unsigned short)r;
}

// packed f32x2 -> bf16x2 (v_cvt_pk_bf16_f32 on gfx950)
__device__ __forceinline__ uint32_t pk2bf(float a, float b) {
  union { __hip_bfloat162 h; uint32_t u; } cv;
  cv.h = __float22bfloat162_rn(make_float2(a, b));
  return cv.u;
}

// async global->LDS, 16B per lane; LDS dest is wave-uniform base + lane*16.
__device__ __forceinline__ void gl_lds16(const unsigned short* g, unsigned short* l) {
  __builtin_amdgcn_global_load_lds(
      (const __attribute__((address_space(1))) void*)g,
      (__attribute__((address_space(3))) void*)l, 16, 0, 0);
}

// One launch: x (blocks 0..4095) + 4 weights (blocks 4096..8191, contiguous dst).
__global__ __launch_bounds__(256) void cvt_all_kernel(
    const float* __restrict__ x,
    const float* __restrict__ w0, const float* __restrict__ w1,
    const float* __restrict__ w2, const float* __restrict__ w3,
    unsigned short* __restrict__ xb, unsigned short* __restrict__ wb) {
  const int bid = blockIdx.x;
  const float* src;
  unsigned short* dst;
  int idx;
  if (bid < 4096) {
    src = x; dst = xb;
    idx = bid * 256 + threadIdx.x;
  } else {
    int j = (bid - 4096) * 256 + threadIdx.x;  // float4 index across 4 weights
    int z = j >> 18;                           // 262144 float4 per weight
    src = (z == 0) ? w0 : (z == 1) ? w1 : (z == 2) ? w2 : w3;
    dst = wb + (size_t)z * 1048576;            // 1M shorts per weight
    idx = j & 262143;
  }
  float4v f = ((const float4v*)src)[idx];
  ushort4v o;
#pragma unroll
  for (int q = 0; q < 4; q++) o[q] = f2bf(f[q]);
  ((ushort4v*)dst)[idx] = o;
}

// C = A(bf16 MxK) @ W^T. MT x 128 tile, BK=64, global_load_lds staging.
// LDS layout XOR-swizzled on 16B granules (phys_g = g ^ (row&7)): at 128B row
// stride unswizzled b128 frag reads are 16-way bank conflicts; swizzled 2-way
// (free). Staging side absorbs the swizzle in the precomputed global address.
// QKV epilogue scales Q (z==0) by QSCALE in fp32 before bf16 rounding.
template <bool OUTPROJ, int MT>
__global__ __launch_bounds__(256) void gemm_bt_kernel(
    const unsigned short* __restrict__ A,
    const unsigned short* __restrict__ W0,
    const unsigned short* __restrict__ W1,
    const unsigned short* __restrict__ W2,
    unsigned short* __restrict__ q_dst,
    unsigned short* __restrict__ k_dst,
    unsigned short* __restrict__ v_dst,
    float* __restrict__ f_dst,
    const float* __restrict__ bias) {
  constexpr int K = 1024;
  constexpr int NMB = MT / 32;    // 16-row m-blocks per wave
  constexpr int APASS = MT / 32;  // staging passes for A (32 rows each)
  const int z = blockIdx.z;
  const unsigned short* W = (z == 0) ? W0 : (z == 1) ? W1 : W2;
  unsigned short* qkv = (z == 0) ? q_dst : (z == 1) ? k_dst : v_dst;

  __shared__ unsigned short Asm[MT * 64];
  __shared__ unsigned short Bsm[128 * 64];

  const int t = threadIdx.x;
  const int wave = t >> 6, lane = t & 63;
  const int quad = lane >> 4, l16 = lane & 15;
  const int wy = wave >> 1, wx = wave & 1;
  const int row0 = blockIdx.x * MT;
  const int col0 = blockIdx.y * 128;

  float4v zero = {0.f, 0.f, 0.f, 0.f};
  float4v acc[NMB][4];
#pragma unroll
  for (int i = 0; i < NMB; i++)
#pragma unroll
    for (int j = 0; j < 4; j++) acc[i][j] = zero;

  // staging geometry: pass i covers rows i*32..i*32+31; thread t -> row i*32+(t>>3),
  // phys granule t&7, logical granule (t&7)^((t>>3)&7). LDS slot = i*2048 + t*8.
  const int srow = t >> 3;
  const int sgl = ((t & 7) ^ (srow & 7)) << 3;  // logical col in shorts
  const unsigned short* gA[APASS];
  const unsigned short* gB[4];
#pragma unroll
  for (int i = 0; i < APASS; i++)
    gA[i] = A + (size_t)(row0 + i * 32 + srow) * K + sgl;
#pragma unroll
  for (int i = 0; i < 4; i++)
    gB[i] = W + (size_t)(col0 + i * 32 + srow) * K + sgl;

  const int swl = (l16 & 7);  // frag-read swizzle key

  for (int k0 = 0; k0 < K; k0 += 64) {
#pragma unroll
    for (int i = 0; i < APASS; i++) gl_lds16(gA[i] + k0, &Asm[i * 2048 + t * 8]);
#pragma unroll
    for (int i = 0; i < 4; i++) gl_lds16(gB[i] + k0, &Bsm[i * 2048 + t * 8]);
    __syncthreads();
    short8 af[NMB][2], bf[4][2];
#pragma unroll
    for (int ks = 0; ks < 2; ks++) {
#pragma unroll
      for (int mb = 0; mb < NMB; mb++) {
        int row = wy * (MT / 2) + mb * 16 + l16;
        int pg = (ks * 4 + quad) ^ swl;
        af[mb][ks] = *(const short8*)(&Asm[row * 64 + pg * 8]);
      }
#pragma unroll
      for (int nb = 0; nb < 4; nb++) {
        int row = wx * 64 + nb * 16 + l16;
        int pg = (ks * 4 + quad) ^ swl;
        bf[nb][ks] = *(const short8*)(&Bsm[row * 64 + pg * 8]);
      }
    }
#pragma unroll
    for (int ks = 0; ks < 2; ks++)
#pragma unroll
      for (int mb = 0; mb < NMB; mb++)
#pragma unroll
        for (int nb = 0; nb < 4; nb++)
          acc[mb][nb] = __builtin_amdgcn_mfma_f32_16x16x32_bf16(af[mb][ks], bf[nb][ks], acc[mb][nb], 0, 0, 0);
    __syncthreads();
  }

  const float qsc = (!OUTPROJ && z == 0) ? QSCALE : 1.0f;
#pragma unroll
  for (int mb = 0; mb < NMB; mb++) {
#pragma unroll
    for (int nb = 0; nb < 4; nb++) {
#pragma unroll
      for (int r = 0; r < 4; r++) {
        int row = row0 + wy * (MT / 2) + mb * 16 + quad * 4 + r;  // token index
        int o = col0 + wx * 64 + nb * 16 + l16;                   // output feature
        float val = acc[mb][nb][r];
        if (OUTPROJ) {
          f_dst[(size_t)row * 1024 + o] = val + bias[o];
        } else {
          int b = row >> 11, s = row & 2047;
          int h = o >> 6, hd = o & 63;
          qkv[(size_t)((b * Hq + h) * Sq + s) * HDq + hd] = f2bf(val * qsc);
        }
      }
    }
  }
}

// Flash attention v8: anti-convoy via many small independent barrier domains.
// v2/v5/v7 all measured dur ~= SUM of pipe budgets (LDS+VALU+MFMA) -> zero
// cross-pipe overlap: one block-wide barrier per tile re-converges all 8
// waves into the same {ds_read | QK | exp2 | PV} rhythm. v8 keeps total work
// identical but shrinks the block to 256 threads / 4 waves (2 q-groups x 2
// key-groups, 64-q block, 64-key K/V tiles) and LDS to 34.8 KB -> 4
// INDEPENDENT blocks per CU (16 waves/CU = 4/SIMD, unchanged). Barriers sync
// only 4 waves; co-resident blocks drift out of phase, so one block's MFMA
// overlaps another's LDS reads and a third's exp2 (m191 regime -> setprio
// kept on MFMA clusters). All datapaths are the verified v5 ones with
// compile-time indices (v7's runtime-p regression reverted), re-parameterized
// to 64-key tiles: XOR-swizzled K gl_lds staging, sigma-permuted V pack
// (VSTR=72), wk-partial combine epilogue. XCD-swizzled flat grid kept
// (FETCH 4x drop proven in v6/v7): 1024 blocks, bh co-located per XCD.
__global__ __launch_bounds__(256, 4) void attn_kernel(
    const unsigned short* __restrict__ Q,
    const unsigned short* __restrict__ Kg,
    const unsigned short* __restrict__ Vg,
    unsigned short* __restrict__ ctx) {
  constexpr int VSTR = 72;    // Vsm stride (shorts)
  constexpr int KBUF = 4096;  // shorts per K buffer (64 keys x 64 hd, swizzled)
  constexpr int VBUF = 4608;  // shorts per V buffer (64 hd x 72)
  constexpr int QSTR = 68;    // obuf q-dim stride (f32)
  __shared__ __align__(16) unsigned char smem[34816];
  unsigned short* Ksm = (unsigned short*)smem;            // [2][4096]
  unsigned short* Vsm = (unsigned short*)(smem + 16384);  // [2][4608]
  float* obuf = (float*)smem;                             // combine: [64 hd][68 q]
  float* dbuf = (float*)(smem + 17408);                   // combine: [64]

  const int wgid = blockIdx.x;
  const int local = wgid >> 3;
  const int bh = (wgid & 7) * 4 + (local >> 5);  // XCD-co-located bh
  const int q0 = (local & 31) * 64;
  const int t = threadIdx.x;
  const int wave = t >> 6, lane = t & 63;
  const int quad = lane >> 4, l16 = lane & 15;
  const int wq = wave >> 1, wk = wave & 1;
  const int swl = l16 & 7;

  const unsigned short* Qb = Q + (size_t)bh * Sq * HDq;
  const unsigned short* Kb = Kg + (size_t)bh * Sq * HDq;
  const unsigned short* Vb = Vg + (size_t)bh * Sq * HDq;

  // Q fragments: wave's 32 q rows (B-operand of QK^T S^T-trick MFMA)
  short8 qf[2][2];
#pragma unroll
  for (int qb = 0; qb < 2; qb++)
#pragma unroll
    for (int ks = 0; ks < 2; ks++)
      qf[qb][ks] = *(const short8*)(Qb + (size_t)(q0 + wq * 32 + qb * 16 + l16) * HDq + ks * 32 + quad * 8);

  short8 ones;
#pragma unroll
  for (int j = 0; j < 8; j++) ones[j] = (short)0x3F80;  // bf16 1.0

  float4v zero = {0.f, 0.f, 0.f, 0.f};
  float4v of[2][4];   // [qb][hb]; D layout row=q (quad*4+r), col=hd (l16)
  float4v dsum[2];
#pragma unroll
  for (int qb = 0; qb < 2; qb++) {
    dsum[qb] = zero;
#pragma unroll
    for (int hb = 0; hb < 4; hb++) of[qb][hb] = zero;
  }

  // K staging: 2 passes x 256 threads x 16B cover 64 rows. Pass i row =
  // i*32 + (t>>3); XOR swizzle on 16B granules pre-applied to global address.
  const int srow = t >> 3;
  const unsigned short* gK = Kb + (size_t)srow * 64 + (((t & 7) ^ (srow & 7)) << 3);

  // V staging (v5-verified pattern, 64-key tile): thread t covers keys vr2,
  // vr2+1 at hd slice vc8..vc8+7; sigma permutes key -> column so PV B-frags
  // are single b128 reads.
  const int vr2 = (t & 31) * 2;
  const int vc8 = (t >> 5) << 3;
  const int sig = (vr2 & ~31) + (((vr2 >> 2) & 3) << 3) + (((vr2 >> 4) & 1) << 2) + (vr2 & 3);
  const unsigned short* gV = Vb + (size_t)vr2 * HDq + vc8;

  short8 vprA0, vprA1, vprB0, vprB1;  // V prefetch double buffer

#define VLOADA(off) do {                                             \
    const unsigned short* vp = gV + (size_t)(off) * HDq;             \
    vprA0 = *(const short8*)(vp);                                    \
    vprA1 = *(const short8*)(vp + HDq);                              \
  } while (0)

#define VLOADB(off) do {                                             \
    const unsigned short* vp = gV + (size_t)(off) * HDq;             \
    vprB0 = *(const short8*)(vp);                                    \
    vprB1 = *(const short8*)(vp + HDq);                              \
  } while (0)

#define VPACK(bufsel, r0, r1) do {                                   \
    unsigned short* vd = &Vsm[(bufsel) * VBUF + sig];                \
    _Pragma("unroll")                                                \
    for (int j = 0; j < 8; j++) {                                    \
      uint32_t pk = (uint32_t)(unsigned short)r0[j] |                \
                    ((uint32_t)(unsigned short)r1[j] << 16);         \
      *(uint32_t*)(vd + (vc8 + j) * VSTR) = pk;                      \
    }                                                                \
  } while (0)

#define KISSUE(off, bufsel) do {                                     \
    gl_lds16(gK + (size_t)(off) * 64, &Ksm[(bufsel) * KBUF + t * 8]);\
    gl_lds16(gK + (size_t)(off) * 64 + 2048,                         \
             &Ksm[(bufsel) * KBUF + 2048 + t * 8]);                  \
  } while (0)

  // one 64-key tile = one 32-key step per wave (wave owns key half wk).
  // Compile-time BUF -> all LDS addresses fold to base+immediate.
#define PSTEP(BUF) do {                                                        \
    const int kb0 = (BUF) * KBUF + wk * 2048;                                  \
    short8 kf[2][2];                                                           \
    _Pragma("unroll")                                                          \
    for (int s = 0; s < 2; s++)                                                \
      _Pragma("unroll")                                                        \
      for (int ks = 0; ks < 2; ks++)                                           \
        kf[s][ks] = *(const short8*)&Ksm[kb0 + (s * 16 + l16) * 64 + ((ks * 4 + quad) ^ swl) * 8]; \
    short8 pfr[2];                                                             \
    _Pragma("unroll")                                                          \
    for (int qb = 0; qb < 2; qb++) {                                           \
      float4v sa = zero, sb = zero;                                            \
      __builtin_amdgcn_s_setprio(1);                                           \
      _Pragma("unroll")                                                        \
      for (int ks = 0; ks < 2; ks++) {                                         \
        sa = __builtin_amdgcn_mfma_f32_16x16x32_bf16(kf[0][ks], qf[qb][ks], sa, 0, 0, 0); \
        sb = __builtin_amdgcn_mfma_f32_16x16x32_bf16(kf[1][ks], qf[qb][ks], sb, 0, 0, 0); \
      }                                                                        \
      __builtin_amdgcn_s_setprio(0);                                           \
      union { uint32_t u[4]; short8 v; } pw;                                   \
      pw.u[0] = pk2bf(__builtin_amdgcn_exp2f(sa[0]), __builtin_amdgcn_exp2f(sa[1])); \
      pw.u[1] = pk2bf(__builtin_amdgcn_exp2f(sa[2]), __builtin_amdgcn_exp2f(sa[3])); \
      pw.u[2] = pk2bf(__builtin_amdgcn_exp2f(sb[0]), __builtin_amdgcn_exp2f(sb[1])); \
      pw.u[3] = pk2bf(__builtin_amdgcn_exp2f(sb[2]), __builtin_amdgcn_exp2f(sb[3])); \
      pfr[qb] = pw.v;                                                          \
    }                                                                          \
    __builtin_amdgcn_s_setprio(1);                                             \
    _Pragma("unroll")                                                          \
    for (int qb = 0; qb < 2; qb++)                                             \
      dsum[qb] = __builtin_amdgcn_mfma_f32_16x16x32_bf16(pfr[qb], ones, dsum[qb], 0, 0, 0); \
    _Pragma("unroll")                                                          \
    for (int hb = 0; hb < 4; hb++) {                                           \
      short8 vf = *(const short8*)&Vsm[(BUF) * VBUF + wk * 32 + quad * 8 + (hb * 16 + l16) * VSTR]; \
      _Pragma("unroll")                                                        \
      for (int qb = 0; qb < 2; qb++)                                           \
        of[qb][hb] = __builtin_amdgcn_mfma_f32_16x16x32_bf16(pfr[qb], vf, of[qb][hb], 0, 0, 0); \
    }                                                                          \
    __builtin_amdgcn_s_setprio(0);                                             \
  } while (0)

  // prologue: K0 async + V0 pack into buf0; V(64) -> vprB; barrier; K(64) async.
  KISSUE(0, 0);
  VLOADA(0);
  VPACK(0, vprA0, vprA1);
  VLOADB(64);
  __syncthreads();
  KISSUE(64, 1);

  // 2-tile unrolled main loop (64-key tiles); V regs alternate A/B, LDS
  // buffers alternate 0/1. 16 iterations.
  for (int kt = 0; kt < Sq; kt += 128) {
    // tile kt (buf 0)
    if (kt + 128 < Sq) VLOADA(kt + 128);
    PSTEP(0);
    if (kt + 64 < Sq) VPACK(1, vprB0, vprB1);
    __syncthreads();
    if (kt + 128 < Sq) KISSUE(kt + 128, 0);
    // tile kt+64 (buf 1)
    if (kt + 192 < Sq) VLOADB(kt + 192);
    PSTEP(1);
    if (kt + 128 < Sq) VPACK(0, vprA0, vprA1);
    __syncthreads();
    if (kt + 192 < Sq) KISSUE(kt + 192, 1);
  }

  // combine the 2 key-group partials in LDS: obuf[hd][q] f32, float4 stores
  // along q (quad*4+r contiguous). Overlays K/V buffers (safe after barrier).
  if (wk == 0) {
#pragma unroll
    for (int qb = 0; qb < 2; qb++) {
#pragma unroll
      for (int hb = 0; hb < 4; hb++)
        *(float4v*)&obuf[(hb * 16 + l16) * QSTR + wq * 32 + qb * 16 + quad * 4] = of[qb][hb];
      if (l16 == 0)
#pragma unroll
        for (int r = 0; r < 4; r++)
          dbuf[wq * 32 + qb * 16 + quad * 4 + r] = dsum[qb][r];
    }
  }
  __syncthreads();
  if (wk == 1) {
#pragma unroll
    for (int qb = 0; qb < 2; qb++) {
#pragma unroll
      for (int hb = 0; hb < 4; hb++) {
        float4v* pp = (float4v*)&obuf[(hb * 16 + l16) * QSTR + wq * 32 + qb * 16 + quad * 4];
        float4v o = *pp;
        o += of[qb][hb];
        *pp = o;
      }
      if (l16 == 0)
#pragma unroll
        for (int r = 0; r < 4; r++)
          dbuf[wq * 32 + qb * 16 + quad * 4 + r] += dsum[qb][r];
    }
  }
  __syncthreads();

  // final store: thread t -> q row (t&63), 16-hd segment (t>>6)
  const int b = bh >> 4, h = bh & 15;
  const int qq = t & 63, hseg = t >> 6;
  const float dinv = 1.0f / dbuf[qq];
  unsigned short* cp = ctx + ((size_t)(b * Sq + q0 + qq)) * Dq + h * 64 + hseg * 16;
  short8 o8a, o8b;
#pragma unroll
  for (int j = 0; j < 8; j++) o8a[j] = (short)f2bf(obuf[(hseg * 16 + j) * QSTR + qq] * dinv);
#pragma unroll
  for (int j = 0; j < 8; j++) o8b[j] = (short)f2bf(obuf[(hseg * 16 + 8 + j) * QSTR + qq] * dinv);
  *(short8*)cp = o8a;
  *(short8*)(cp + 8) = o8b;
#undef VLOADA
#undef VLOADB
#undef VPACK
#undef KISSUE
#undef PSTEP
}

extern "C" void kernel_launch(void* const* d_in, const int* in_sizes, int n_in,
                              void* d_out, int out_size, void* d_ws, size_t ws_size,
                              hipStream_t stream) {
  (void)in_sizes; (void)n_in; (void)out_size; (void)ws_size;
  const float* x  = (const float*)d_in[0];
  const float* wq = (const float*)d_in[1];
  const float* wk = (const float*)d_in[2];
  const float* wv = (const float*)d_in[3];
  const float* wo = (const float*)d_in[4];
  const float* bo = (const float*)d_in[5];
  float* out = (float*)d_out;

  char* ws = (char*)d_ws;
  const size_t MB = 1u << 20;
  unsigned short* xb  = (unsigned short*)(ws + 0 * MB);   // 8 MB  (4096x1024 bf16)
  unsigned short* wqb = (unsigned short*)(ws + 8 * MB);   // 2 MB each, contiguous
  unsigned short* wkb = (unsigned short*)(ws + 10 * MB);
  unsigned short* wvb = (unsigned short*)(ws + 12 * MB);
  unsigned short* wob = (unsigned short*)(ws + 14 * MB);
  unsigned short* qb  = (unsigned short*)(ws + 16 * MB);  // 8 MB  (B,H,S,HD), pre-scaled
  unsigned short* kb  = (unsigned short*)(ws + 24 * MB);  // 8 MB
  unsigned short* vb  = (unsigned short*)(ws + 32 * MB);  // 8 MB
  unsigned short* cxb = (unsigned short*)(ws + 40 * MB);  // 8 MB  (B,S,D)

  cvt_all_kernel<<<8192, 256, 0, stream>>>(x, wq, wk, wv, wo, xb, wqb);

  gemm_bt_kernel<false, 128><<<dim3(32, 8, 3), 256, 0, stream>>>(
      xb, wqb, wkb, wvb, qb, kb, vb, nullptr, nullptr);
  attn_kernel<<<dim3(1024), 256, 0, stream>>>(qb, kb, vb, cxb);
  gemm_bt_kernel<true, 64><<<dim3(64, 8, 1), 256, 0, stream>>>(
      cxb, wob, wob, wob, nullptr, nullptr, nullptr, out, bo);
}

// Round 8
// 180.047 us; speedup vs baseline: 1.2652x; 1.0374x over previous
//
#include <hip/hip_runtime.h>
#include <hip/hip_bf16.h>
#include <stdint.h>

typedef __attribute__((ext_vector_type(8))) short short8;
typedef __attribute__((ext_vector_type(4))) float float4v;
typedef __attribute__((ext_vector_type(4))) unsigned short ushort4v;

#define Bq 2
#define Sq 2048
#define Dq 1024
#define Hq 16
#define HDq 64

// 0.125 * log2(e): folded into Q at the QKV-GEMM epilogue so attention can use
// exp2 directly with no per-score scaling.
#define QSCALE 0.18033688011112042f

__device__ __forceinline__ unsigned short f2bf(float f) {
  union { float f; uint32_t u; } v; v.f = f;
  uint32_t r = (v.u + 0x7FFFu + ((v.u >> 16) & 1u)) >> 16;
  return (unsigned short)r;
}

// packed f32x2 -> bf16x2 (v_cvt_pk_bf16_f32 on gfx950)
__device__ __forceinline__ uint32_t pk2bf(float a, float b) {
  union { __hip_bfloat162 h; uint32_t u; } cv;
  cv.h = __float22bfloat162_rn(make_float2(a, b));
  return cv.u;
}

// async global->LDS, 16B per lane; LDS dest is wave-uniform base + lane*16.
__device__ __forceinline__ void gl_lds16(const unsigned short* g, unsigned short* l) {
  __builtin_amdgcn_global_load_lds(
      (const __attribute__((address_space(1))) void*)g,
      (__attribute__((address_space(3))) void*)l, 16, 0, 0);
}

// One launch: x (blocks 0..4095) + 4 weights (blocks 4096..8191, contiguous dst).
__global__ __launch_bounds__(256) void cvt_all_kernel(
    const float* __restrict__ x,
    const float* __restrict__ w0, const float* __restrict__ w1,
    const float* __restrict__ w2, const float* __restrict__ w3,
    unsigned short* __restrict__ xb, unsigned short* __restrict__ wb) {
  const int bid = blockIdx.x;
  const float* src;
  unsigned short* dst;
  int idx;
  if (bid < 4096) {
    src = x; dst = xb;
    idx = bid * 256 + threadIdx.x;
  } else {
    int j = (bid - 4096) * 256 + threadIdx.x;  // float4 index across 4 weights
    int z = j >> 18;                           // 262144 float4 per weight
    src = (z == 0) ? w0 : (z == 1) ? w1 : (z == 2) ? w2 : w3;
    dst = wb + (size_t)z * 1048576;            // 1M shorts per weight
    idx = j & 262143;
  }
  float4v f = ((const float4v*)src)[idx];
  ushort4v o;
#pragma unroll
  for (int q = 0; q < 4; q++) o[q] = f2bf(f[q]);
  ((ushort4v*)dst)[idx] = o;
}

// C = A(bf16 MxK) @ W^T. MT x 128 tile, BK=64, global_load_lds staging.
// LDS layout XOR-swizzled on 16B granules (phys_g = g ^ (row&7)).
// QKV epilogue: z==0 (Q) scales by QSCALE; z==2 (V) stores TRANSPOSED +
// sigma-permuted layout [bh][hd][sig(s)] so attention can stage V via
// global_load_lds with zero pack work. Each lane holds 4 consecutive tokens
// (quad*4+r) at fixed feature o; sigma keeps 4-aligned groups contiguous, so
// the store is one packed b64 at column sig(s0).
template <bool OUTPROJ, int MT>
__global__ __launch_bounds__(256) void gemm_bt_kernel(
    const unsigned short* __restrict__ A,
    const unsigned short* __restrict__ W0,
    const unsigned short* __restrict__ W1,
    const unsigned short* __restrict__ W2,
    unsigned short* __restrict__ q_dst,
    unsigned short* __restrict__ k_dst,
    unsigned short* __restrict__ v_dst,
    float* __restrict__ f_dst,
    const float* __restrict__ bias) {
  constexpr int K = 1024;
  constexpr int NMB = MT / 32;    // 16-row m-blocks per wave
  constexpr int APASS = MT / 32;  // staging passes for A (32 rows each)
  const int z = blockIdx.z;
  const unsigned short* W = (z == 0) ? W0 : (z == 1) ? W1 : W2;
  unsigned short* qkv = (z == 0) ? q_dst : (z == 1) ? k_dst : v_dst;

  __shared__ unsigned short Asm[MT * 64];
  __shared__ unsigned short Bsm[128 * 64];

  const int t = threadIdx.x;
  const int wave = t >> 6, lane = t & 63;
  const int quad = lane >> 4, l16 = lane & 15;
  const int wy = wave >> 1, wx = wave & 1;
  const int row0 = blockIdx.x * MT;
  const int col0 = blockIdx.y * 128;

  float4v zero = {0.f, 0.f, 0.f, 0.f};
  float4v acc[NMB][4];
#pragma unroll
  for (int i = 0; i < NMB; i++)
#pragma unroll
    for (int j = 0; j < 4; j++) acc[i][j] = zero;

  // staging geometry: pass i covers rows i*32..i*32+31; thread t -> row i*32+(t>>3),
  // phys granule t&7, logical granule (t&7)^((t>>3)&7). LDS slot = i*2048 + t*8.
  const int srow = t >> 3;
  const int sgl = ((t & 7) ^ (srow & 7)) << 3;  // logical col in shorts
  const unsigned short* gA[APASS];
  const unsigned short* gB[4];
#pragma unroll
  for (int i = 0; i < APASS; i++)
    gA[i] = A + (size_t)(row0 + i * 32 + srow) * K + sgl;
#pragma unroll
  for (int i = 0; i < 4; i++)
    gB[i] = W + (size_t)(col0 + i * 32 + srow) * K + sgl;

  const int swl = (l16 & 7);  // frag-read swizzle key

  for (int k0 = 0; k0 < K; k0 += 64) {
#pragma unroll
    for (int i = 0; i < APASS; i++) gl_lds16(gA[i] + k0, &Asm[i * 2048 + t * 8]);
#pragma unroll
    for (int i = 0; i < 4; i++) gl_lds16(gB[i] + k0, &Bsm[i * 2048 + t * 8]);
    __syncthreads();
    short8 af[NMB][2], bf[4][2];
#pragma unroll
    for (int ks = 0; ks < 2; ks++) {
#pragma unroll
      for (int mb = 0; mb < NMB; mb++) {
        int row = wy * (MT / 2) + mb * 16 + l16;
        int pg = (ks * 4 + quad) ^ swl;
        af[mb][ks] = *(const short8*)(&Asm[row * 64 + pg * 8]);
      }
#pragma unroll
      for (int nb = 0; nb < 4; nb++) {
        int row = wx * 64 + nb * 16 + l16;
        int pg = (ks * 4 + quad) ^ swl;
        bf[nb][ks] = *(const short8*)(&Bsm[row * 64 + pg * 8]);
      }
    }
#pragma unroll
    for (int ks = 0; ks < 2; ks++)
#pragma unroll
      for (int mb = 0; mb < NMB; mb++)
#pragma unroll
        for (int nb = 0; nb < 4; nb++)
          acc[mb][nb] = __builtin_amdgcn_mfma_f32_16x16x32_bf16(af[mb][ks], bf[nb][ks], acc[mb][nb], 0, 0, 0);
    __syncthreads();
  }

  const float qsc = (!OUTPROJ && z == 0) ? QSCALE : 1.0f;
#pragma unroll
  for (int mb = 0; mb < NMB; mb++) {
#pragma unroll
    for (int nb = 0; nb < 4; nb++) {
      if (OUTPROJ) {
#pragma unroll
        for (int r = 0; r < 4; r++) {
          int row = row0 + wy * (MT / 2) + mb * 16 + quad * 4 + r;
          int o = col0 + wx * 64 + nb * 16 + l16;
          f_dst[(size_t)row * 1024 + o] = acc[mb][nb][r] + bias[o];
        }
      } else if (z == 2) {
        // V^T + sigma: rowb = 4-aligned token base (b constant across r).
        int rowb = row0 + wy * (MT / 2) + mb * 16 + quad * 4;
        int b = rowb >> 11, s0 = rowb & 2047;
        int o = col0 + wx * 64 + nb * 16 + l16;
        int h = o >> 6, hd = o & 63;
        int c = (s0 & ~31) + (((s0 >> 2) & 3) << 3) + (((s0 >> 4) & 1) << 2);
        ushort4v p4;
#pragma unroll
        for (int r = 0; r < 4; r++) p4[r] = f2bf(acc[mb][nb][r]);
        *(ushort4v*)(qkv + ((size_t)((b * Hq + h) * HDq + hd)) * Sq + c) = p4;
      } else {
#pragma unroll
        for (int r = 0; r < 4; r++) {
          int row = row0 + wy * (MT / 2) + mb * 16 + quad * 4 + r;
          int o = col0 + wx * 64 + nb * 16 + l16;
          int b = row >> 11, s = row & 2047;
          int h = o >> 6, hd = o & 63;
          qkv[(size_t)((b * Hq + h) * Sq + s) * HDq + hd] = f2bf(acc[mb][nb][r] * qsc);
        }
      }
    }
  }
}

// Flash attention v9: V pack eliminated — V arrives pre-transposed +
// pre-sigma'd from the QKV GEMM ([bh][hd][sig(s)]), so V staging is a clone
// of the verified K path: global_load_lds, XOR-swizzled granules, zero VALU,
// zero ds_writes, no prefetch registers. This removes the ds_write_b32
// scatter that saturated the per-CU LDS pipe (the constant 2.16M
// bank-conflict signature of v5/v7/v8).
// Structure otherwise = v5 exactly (best measured): 512 threads, 8 waves =
// 4 q-groups x 2 key-groups, 128-key tiles, double-buffered, one barrier per
// tile, wk-partial combine epilogue. XCD-swizzled flat grid (FETCH 4x drop).
// V^T tile [64 hd][128 keys]: rows 256B -> 16 granules/row; staging thread t
// covers row t>>4 (pass adds 32), phys granule t&15, logical granule
// (t&15)^(row&15) pre-swizzled into the global column. Frag read: row
// hb*16+l16, logical granule wk*8+p*4+quad, phys = lg ^ l16 -> 2-way banks.
// Key order inside the b128 frag = sig^-1(quad*8..+7) = {quad*4+0..3,
// 16+quad*4+0..3} = pfr's pack order (v5-verified mapping, now via global
// sigma instead of LDS-side pack).
__global__ __launch_bounds__(512, 4) void attn_kernel(
    const unsigned short* __restrict__ Q,
    const unsigned short* __restrict__ Kg,
    const unsigned short* __restrict__ Vt,
    unsigned short* __restrict__ ctx) {
  constexpr int KBUF = 8192;  // shorts per K buffer (128 keys x 64 hd, swizzled)
  constexpr int VBUF = 8192;  // shorts per V^T buffer (64 hd x 128 keys, swizzled)
  constexpr int QSTR = 132;   // obuf q-dim stride (f32)
  __shared__ __align__(16) unsigned char smem[65536];
  unsigned short* Ksm = (unsigned short*)smem;            // [2][8192]
  unsigned short* Vsm = (unsigned short*)(smem + 32768);  // [2][8192]
  float* obuf = (float*)smem;                             // combine: [64 hd][132 q]
  float* dbuf = (float*)(smem + 33792);                   // combine: [128]

  const int wgid = blockIdx.x;
  const int lid = wgid >> 3;
  const int bh = (wgid & 7) * 4 + (lid >> 4);  // XCD-co-located bh
  const int q0 = (lid & 15) * 128;
  const int t = threadIdx.x;
  const int wave = t >> 6, lane = t & 63;
  const int quad = lane >> 4, l16 = lane & 15;
  const int wq = wave >> 1, wk = wave & 1;
  const int swl = l16 & 7;

  const unsigned short* Qb = Q + (size_t)bh * Sq * HDq;
  const unsigned short* Kb = Kg + (size_t)bh * Sq * HDq;
  const unsigned short* Vb = Vt + (size_t)bh * HDq * Sq;  // V^T base

  // Q fragments: wave's 32 q rows (B-operand of QK^T S^T-trick MFMA)
  short8 qf[2][2];
#pragma unroll
  for (int qb = 0; qb < 2; qb++)
#pragma unroll
    for (int ks = 0; ks < 2; ks++)
      qf[qb][ks] = *(const short8*)(Qb + (size_t)(q0 + wq * 32 + qb * 16 + l16) * HDq + ks * 32 + quad * 8);

  short8 ones;
#pragma unroll
  for (int j = 0; j < 8; j++) ones[j] = (short)0x3F80;  // bf16 1.0

  float4v zero = {0.f, 0.f, 0.f, 0.f};
  float4v of[2][4];   // [qb][hb]; D layout row=q (quad*4+r), col=hd (l16)
  float4v dsum[2];
#pragma unroll
  for (int qb = 0; qb < 2; qb++) {
    dsum[qb] = zero;
#pragma unroll
    for (int hb = 0; hb < 4; hb++) of[qb][hb] = zero;
  }

  // K staging: 2 passes x 512 threads x 16B; pass i row = i*64 + (t>>3);
  // XOR swizzle on 8 granules pre-applied to the global address.
  const int srow = t >> 3;
  const unsigned short* gK = Kb + (size_t)srow * 64 + (((t & 7) ^ (srow & 7)) << 3);

  // V^T staging: 2 passes; pass i covers hd rows i*32 + (t>>4); 16 granules
  // per 256B row, logical granule (t&15)^(row&15) pre-applied (row&15 is
  // pass-invariant).
  const int vrow = t >> 4;
  const unsigned short* gV = Vb + (size_t)vrow * Sq + (((t & 15) ^ (vrow & 15)) << 3);

#define KISSUE(off, bufsel) do {                                     \
    gl_lds16(gK + (size_t)(off) * 64, &Ksm[(bufsel) * KBUF + t * 8]);\
    gl_lds16(gK + (size_t)(off) * 64 + 4096,                         \
             &Ksm[(bufsel) * KBUF + 4096 + t * 8]);                  \
  } while (0)

#define VISSUE(off, bufsel) do {                                     \
    gl_lds16(gV + (off), &Vsm[(bufsel) * VBUF + t * 8]);             \
    gl_lds16(gV + (off) + 32 * Sq,                                   \
             &Vsm[(bufsel) * VBUF + 4096 + t * 8]);                  \
  } while (0)

  // one 32-key substep: v5's verified QK/exp2/pack/dsum; vf now reads the
  // swizzled V^T tile (same key order as v5's sigma layout).
#define PSTEP(P, BUF) do {                                                     \
    const int kb0 = (BUF) * KBUF + wk * 4096 + (P) * 2048;                     \
    short8 kf[2][2];                                                           \
    _Pragma("unroll")                                                          \
    for (int s = 0; s < 2; s++)                                                \
      _Pragma("unroll")                                                        \
      for (int ks = 0; ks < 2; ks++)                                           \
        kf[s][ks] = *(const short8*)&Ksm[kb0 + (s * 16 + l16) * 64 + ((ks * 4 + quad) ^ swl) * 8]; \
    short8 pfr[2];                                                             \
    _Pragma("unroll")                                                          \
    for (int qb = 0; qb < 2; qb++) {                                           \
      float4v sa = zero, sb = zero;                                            \
      _Pragma("unroll")                                                        \
      for (int ks = 0; ks < 2; ks++) {                                         \
        sa = __builtin_amdgcn_mfma_f32_16x16x32_bf16(kf[0][ks], qf[qb][ks], sa, 0, 0, 0); \
        sb = __builtin_amdgcn_mfma_f32_16x16x32_bf16(kf[1][ks], qf[qb][ks], sb, 0, 0, 0); \
      }                                                                        \
      union { uint32_t u[4]; short8 v; } pw;                                   \
      pw.u[0] = pk2bf(__builtin_amdgcn_exp2f(sa[0]), __builtin_amdgcn_exp2f(sa[1])); \
      pw.u[1] = pk2bf(__builtin_amdgcn_exp2f(sa[2]), __builtin_amdgcn_exp2f(sa[3])); \
      pw.u[2] = pk2bf(__builtin_amdgcn_exp2f(sb[0]), __builtin_amdgcn_exp2f(sb[1])); \
      pw.u[3] = pk2bf(__builtin_amdgcn_exp2f(sb[2]), __builtin_amdgcn_exp2f(sb[3])); \
      pfr[qb] = pw.v;                                                          \
    }                                                                          \
    _Pragma("unroll")                                                          \
    for (int qb = 0; qb < 2; qb++)                                             \
      dsum[qb] = __builtin_amdgcn_mfma_f32_16x16x32_bf16(pfr[qb], ones, dsum[qb], 0, 0, 0); \
    _Pragma("unroll")                                                          \
    for (int hb = 0; hb < 4; hb++) {                                           \
      short8 vf = *(const short8*)&Vsm[(BUF) * VBUF + (hb * 16 + l16) * 128 + ((wk * 8 + (P) * 4 + quad) ^ l16) * 8]; \
      _Pragma("unroll")                                                        \
      for (int qb = 0; qb < 2; qb++)                                           \
        of[qb][hb] = __builtin_amdgcn_mfma_f32_16x16x32_bf16(pfr[qb], vf, of[qb][hb], 0, 0, 0); \
    }                                                                          \
  } while (0)

  // prologue: tile 0 into buf0; barrier drains; tile 1 into buf1 (in flight
  // during tile-0 compute, drained by the in-loop barrier).
  KISSUE(0, 0);
  VISSUE(0, 0);
  __syncthreads();
  KISSUE(128, 1);
  VISSUE(128, 1);

  for (int kt = 0; kt < Sq; kt += 128) {
    const int cur = (kt >> 7) & 1;
    PSTEP(0, cur);
    PSTEP(1, cur);
    __syncthreads();
    if (kt + 256 < Sq) {
      KISSUE(kt + 256, cur);
      VISSUE(kt + 256, cur);
    }
  }

  // combine the 2 key-group partials in LDS: obuf[hd][q] f32, float4 stores
  // along q (quad*4+r contiguous). Overlays K/V buffers (safe after barrier).
  if (wk == 0) {
#pragma unroll
    for (int qb = 0; qb < 2; qb++) {
#pragma unroll
      for (int hb = 0; hb < 4; hb++)
        *(float4v*)&obuf[(hb * 16 + l16) * QSTR + wq * 32 + qb * 16 + quad * 4] = of[qb][hb];
      if (l16 == 0)
#pragma unroll
        for (int r = 0; r < 4; r++)
          dbuf[wq * 32 + qb * 16 + quad * 4 + r] = dsum[qb][r];
    }
  }
  __syncthreads();
  if (wk == 1) {
#pragma unroll
    for (int qb = 0; qb < 2; qb++) {
#pragma unroll
      for (int hb = 0; hb < 4; hb++) {
        float4v* pp = (float4v*)&obuf[(hb * 16 + l16) * QSTR + wq * 32 + qb * 16 + quad * 4];
        float4v o = *pp;
        o += of[qb][hb];
        *pp = o;
      }
      if (l16 == 0)
#pragma unroll
        for (int r = 0; r < 4; r++)
          dbuf[wq * 32 + qb * 16 + quad * 4 + r] += dsum[qb][r];
    }
  }
  __syncthreads();

  // final store: thread t -> q row (t&127), 16-hd segment (t>>7)
  const int b = bh >> 4, h = bh & 15;
  const int qq = t & 127, hseg = t >> 7;
  const float dinv = 1.0f / dbuf[qq];
  unsigned short* cp = ctx + ((size_t)(b * Sq + q0 + qq)) * Dq + h * 64 + hseg * 16;
  short8 o8a, o8b;
#pragma unroll
  for (int j = 0; j < 8; j++) o8a[j] = (short)f2bf(obuf[(hseg * 16 + j) * QSTR + qq] * dinv);
#pragma unroll
  for (int j = 0; j < 8; j++) o8b[j] = (short)f2bf(obuf[(hseg * 16 + 8 + j) * QSTR + qq] * dinv);
  *(short8*)cp = o8a;
  *(short8*)(cp + 8) = o8b;
#undef KISSUE
#undef VISSUE
#undef PSTEP
}

extern "C" void kernel_launch(void* const* d_in, const int* in_sizes, int n_in,
                              void* d_out, int out_size, void* d_ws, size_t ws_size,
                              hipStream_t stream) {
  (void)in_sizes; (void)n_in; (void)out_size; (void)ws_size;
  const float* x  = (const float*)d_in[0];
  const float* wq = (const float*)d_in[1];
  const float* wk = (const float*)d_in[2];
  const float* wv = (const float*)d_in[3];
  const float* wo = (const float*)d_in[4];
  const float* bo = (const float*)d_in[5];
  float* out = (float*)d_out;

  char* ws = (char*)d_ws;
  const size_t MB = 1u << 20;
  unsigned short* xb  = (unsigned short*)(ws + 0 * MB);   // 8 MB  (4096x1024 bf16)
  unsigned short* wqb = (unsigned short*)(ws + 8 * MB);   // 2 MB each, contiguous
  unsigned short* wkb = (unsigned short*)(ws + 10 * MB);
  unsigned short* wvb = (unsigned short*)(ws + 12 * MB);
  unsigned short* wob = (unsigned short*)(ws + 14 * MB);
  unsigned short* qb  = (unsigned short*)(ws + 16 * MB);  // 8 MB  (B,H,S,HD), pre-scaled
  unsigned short* kb  = (unsigned short*)(ws + 24 * MB);  // 8 MB
  unsigned short* vb  = (unsigned short*)(ws + 32 * MB);  // 8 MB  (B,H,HD,sig(S)) V^T
  unsigned short* cxb = (unsigned short*)(ws + 40 * MB);  // 8 MB  (B,S,D)

  cvt_all_kernel<<<8192, 256, 0, stream>>>(x, wq, wk, wv, wo, xb, wqb);

  gemm_bt_kernel<false, 128><<<dim3(32, 8, 3), 256, 0, stream>>>(
      xb, wqb, wkb, wvb, qb, kb, vb, nullptr, nullptr);
  attn_kernel<<<dim3(512), 512, 0, stream>>>(qb, kb, vb, cxb);
  gemm_bt_kernel<true, 64><<<dim3(64, 8, 1), 256, 0, stream>>>(
      cxb, wob, wob, wob, nullptr, nullptr, nullptr, out, bo);
}